// Round 11
// baseline (388.025 us; speedup 1.0000x reference)
//
#include <hip/hip_runtime.h>
#include <hip/hip_bf16.h>

typedef float    f4v    __attribute__((ext_vector_type(4)));
typedef short    short8 __attribute__((ext_vector_type(8)));
typedef unsigned u2v    __attribute__((ext_vector_type(2)));
typedef unsigned u4v    __attribute__((ext_vector_type(4)));

constexpr int Bn = 4096, TR = 16;

// ---- split-bf16 helpers ----------------------------------------------------
__device__ inline unsigned cvt2(float x, float y) {
  union { __hip_bfloat162 h; unsigned u; } c;
  c.h = __float22bfloat162_rn(float2{x, y});
  return c.u;   // low16 = bf16(x), high16 = bf16(y)
}
__device__ inline void split_pair(float x, float y, unsigned& hp, unsigned& lp) {
  hp = cvt2(x, y);
  float hx = __uint_as_float(hp << 16);
  float hy = __uint_as_float(hp & 0xffff0000u);
  lp = cvt2(x - hx, y - hy);
}
union S8U { unsigned u[4]; short8 s; u4v v4; };
__device__ inline void split8(const float v[8], short8& hi, short8& lo) {
  S8U h, l;
  #pragma unroll
  for (int d = 0; d < 4; ++d) split_pair(v[2 * d], v[2 * d + 1], h.u[d], l.u[d]);
  hi = h.s; lo = l.s;
}
__device__ inline void split8p(const float* p, short8& hi, short8& lo) {
  f4v a = *(const f4v*)p, b = *(const f4v*)(p + 4);
  float v[8] = {a[0], a[1], a[2], a[3], b[0], b[1], b[2], b[3]};
  split8(v, hi, lo);
}
__device__ inline f4v mfma16(short8 a, short8 b, f4v c) {
  return __builtin_amdgcn_mfma_f32_16x16x32_bf16(a, b, c, 0, 0, 0);
}
__device__ __attribute__((always_inline)) inline f4v gdot8(
    const short8 (&ah)[8], const short8 (&al)[8],
    const short8 (&bh)[8], const short8 (&bl)[8]) {
  f4v c = {0.f, 0.f, 0.f, 0.f};
  #pragma unroll
  for (int s = 0; s < 8; ++s) {
    c = mfma16(ah[s], bh[s], c);
    c = mfma16(al[s], bh[s], c);
    c = mfma16(ah[s], bl[s], c);
  }
  return c;
}

// ---------------------------------------------------------------------------
// k_prep: KAT[n][m] = (inv(A A^T + 1e-6 I) @ A)^T -> d_ws. 1 block, 256 thr.
// (verified: G via MFMA, Gauss-Jordan on wave 0 via unrolled shuffles.)
// ---------------------------------------------------------------------------
__global__ __launch_bounds__(256) void k_prep(const float* __restrict__ A,
                                              float* __restrict__ KAT) {
  __shared__ __align__(16) float As[32 * 256];
  __shared__ float Gm[32 * 68];
  __shared__ float GinvL[32 * 32];

  const int t = threadIdx.x;
  const int lane = t & 63, wv = t >> 6, quad = lane >> 4, l15 = lane & 15;
  const int T = wv & 1, kh = wv >> 1;

  for (int i = t; i < 2048; i += 256)
    ((f4v*)As)[i] = ((const f4v*)A)[i];
  __syncthreads();

  {
    short8 afh[2][8], afl[2][8];
    #pragma unroll
    for (int tt = 0; tt < 2; ++tt)
      #pragma unroll
      for (int s = 0; s < 8; ++s)
        split8p(As + (l15 + 16 * tt) * 256 + 32 * s + 8 * quad,
                afh[tt][s], afl[tt][s]);
    f4v cg;
    if      (wv == 0) cg = gdot8(afh[0], afl[0], afh[0], afl[0]);
    else if (wv == 1) cg = gdot8(afh[1], afl[1], afh[0], afl[0]);
    else if (wv == 2) cg = gdot8(afh[0], afl[0], afh[1], afl[1]);
    else              cg = gdot8(afh[1], afl[1], afh[1], afl[1]);
    #pragma unroll
    for (int r = 0; r < 4; ++r) {
      int gi = 16 * T + 4 * quad + r, gj = 16 * kh + l15;
      Gm[gi * 68 + gj]      = cg[r] + (gi == gj ? 1e-6f : 0.f);
      Gm[gi * 68 + 32 + gj] = (gi == gj) ? 1.f : 0.f;
    }
  }
  __syncthreads();

  if (wv == 0) {
    float gcol[32];
    #pragma unroll
    for (int i = 0; i < 32; ++i) gcol[i] = Gm[i * 68 + lane];
    #pragma unroll
    for (int k = 0; k < 32; ++k) {
      float ckk  = __shfl(gcol[k], k);
      float ipiv = 1.f / ckk;
      float pivj = gcol[k] * ipiv;
      gcol[k] = pivj;
      #pragma unroll
      for (int i = 0; i < 32; ++i) {
        if (i == k) continue;
        float cki = __shfl(gcol[i], k);
        gcol[i] = fmaf(-cki, pivj, gcol[i]);
      }
    }
    if (lane >= 32) {
      #pragma unroll
      for (int i = 0; i < 32; ++i) GinvL[i * 32 + (lane - 32)] = gcol[i];
    }
  }
  __syncthreads();

  {
    float res[32];
    #pragma unroll
    for (int m = 0; m < 32; ++m) res[m] = 0.f;
    for (int p = 0; p < 32; ++p) {
      float av = As[p * 256 + t];
      #pragma unroll
      for (int m4 = 0; m4 < 8; ++m4) {
        f4v g = *(const f4v*)&GinvL[p * 32 + 4 * m4];
        res[4 * m4 + 0] = fmaf(av, g[0], res[4 * m4 + 0]);
        res[4 * m4 + 1] = fmaf(av, g[1], res[4 * m4 + 1]);
        res[4 * m4 + 2] = fmaf(av, g[2], res[4 * m4 + 2]);
        res[4 * m4 + 3] = fmaf(av, g[3], res[4 * m4 + 3]);
      }
    }
    #pragma unroll
    for (int m4 = 0; m4 < 8; ++m4) {
      f4v v = {res[4 * m4], res[4 * m4 + 1], res[4 * m4 + 2], res[4 * m4 + 3]};
      *(f4v*)&KAT[t * 32 + 4 * m4] = v;
    }
  }
}

// ---------------------------------------------------------------------------
// k_main: 256 threads, TR=16, grid 256. All 4 waves: MLP + stage pre-split
// KAT fragments into LDS. Then waves 1-3 EXIT; wave 0 runs all 100 DR
// iterations solo with ZERO barriers (all LDS dependencies are same-wave,
// ordered by compiler-inserted lgkmcnt waits).
// ---------------------------------------------------------------------------
__global__ __launch_bounds__(256, 1) void k_main(
    const float* __restrict__ x,  const float* __restrict__ bmat,
    const float* __restrict__ W1, const float* __restrict__ b1,
    const float* __restrict__ W2, const float* __restrict__ b2,
    const float* __restrict__ W3, const float* __restrict__ b3,
    const float* __restrict__ A,  const float* __restrict__ KAT,
    const int* __restrict__ n_iter_p, float* __restrict__ out) {

  __shared__ __align__(16) float    ubuf[8768];    // MLP scratch; ys persists
  __shared__ __align__(16) unsigned zfrag[4096];   // z frags [s][hi/lo][1KB]
  __shared__ __align__(16) unsigned kfh[4096];     // KAT frag hi: [U][lane*4]
  __shared__ __align__(16) unsigned kfl[4096];     // KAT frag lo
  __shared__ __align__(16) float    rb[576];       // wave-0 r roundtrip [16][36]

  const int t = threadIdx.x;
  const int lane = t & 63, wv = t >> 6, quad = lane >> 4, l15 = lane & 15;
  const int row0 = blockIdx.x * TR;

  float* xs = ubuf;            // [16][132]
  float* h1 = ubuf + 2112;     // [16][208]
  float* h2 = ubuf + 5440;     // [16][208]
  float* ys = ubuf;            // [16][260] (xs+h1 dead by then)

  {
    int r = t >> 4, c8 = t & 15;
    *(f4v*)&xs[r * 132 + 8 * c8]     = *(const f4v*)&x[(size_t)(row0 + r) * 128 + 8 * c8];
    *(f4v*)&xs[r * 132 + 8 * c8 + 4] = *(const f4v*)&x[(size_t)(row0 + r) * 128 + 8 * c8 + 4];
  }
  __syncthreads();

  // ---- MLP: 4 rows per wave (verified register-blocked form) ----
  {
    const int rg = wv, oc = lane;
    const bool g3 = (oc < 8);    // HID=200: col oc+192 valid iff oc<8
    float acc[4][4];

    #pragma unroll
    for (int oi = 0; oi < 4; ++oi)
      #pragma unroll
      for (int r = 0; r < 4; ++r) acc[oi][r] = 0.f;
    for (int k4 = 0; k4 < 32; ++k4) {
      float xv[4][4];
      #pragma unroll
      for (int r = 0; r < 4; ++r) {
        f4v v = *(const f4v*)&xs[(4 * rg + r) * 132 + 4 * k4];
        xv[r][0] = v[0]; xv[r][1] = v[1]; xv[r][2] = v[2]; xv[r][3] = v[3];
      }
      #pragma unroll
      for (int kk = 0; kk < 4; ++kk) {
        const float* wr = W1 + (4 * k4 + kk) * 200 + oc;
        float w0 = wr[0], w1c = wr[64], w2c = wr[128];
        float w3c = g3 ? wr[192] : 0.f;
        #pragma unroll
        for (int r = 0; r < 4; ++r) {
          acc[0][r] = fmaf(xv[r][kk], w0, acc[0][r]);
          acc[1][r] = fmaf(xv[r][kk], w1c, acc[1][r]);
          acc[2][r] = fmaf(xv[r][kk], w2c, acc[2][r]);
          acc[3][r] = fmaf(xv[r][kk], w3c, acc[3][r]);
        }
      }
    }
    #pragma unroll
    for (int oi = 0; oi < 4; ++oi) {
      if (oi == 3 && !g3) continue;
      float bb = b1[oc + 64 * oi];
      #pragma unroll
      for (int r = 0; r < 4; ++r)
        h1[(4 * rg + r) * 208 + oc + 64 * oi] = fmaxf(acc[oi][r] + bb, 0.f);
    }
    __syncthreads();

    #pragma unroll
    for (int oi = 0; oi < 4; ++oi)
      #pragma unroll
      for (int r = 0; r < 4; ++r) acc[oi][r] = 0.f;
    for (int k4 = 0; k4 < 50; ++k4) {
      float xv[4][4];
      #pragma unroll
      for (int r = 0; r < 4; ++r) {
        f4v v = *(const f4v*)&h1[(4 * rg + r) * 208 + 4 * k4];
        xv[r][0] = v[0]; xv[r][1] = v[1]; xv[r][2] = v[2]; xv[r][3] = v[3];
      }
      #pragma unroll
      for (int kk = 0; kk < 4; ++kk) {
        const float* wr = W2 + (4 * k4 + kk) * 200 + oc;
        float w0 = wr[0], w1c = wr[64], w2c = wr[128];
        float w3c = g3 ? wr[192] : 0.f;
        #pragma unroll
        for (int r = 0; r < 4; ++r) {
          acc[0][r] = fmaf(xv[r][kk], w0, acc[0][r]);
          acc[1][r] = fmaf(xv[r][kk], w1c, acc[1][r]);
          acc[2][r] = fmaf(xv[r][kk], w2c, acc[2][r]);
          acc[3][r] = fmaf(xv[r][kk], w3c, acc[3][r]);
        }
      }
    }
    #pragma unroll
    for (int oi = 0; oi < 4; ++oi) {
      if (oi == 3 && !g3) continue;
      float bb = b2[oc + 64 * oi];
      #pragma unroll
      for (int r = 0; r < 4; ++r)
        h2[(4 * rg + r) * 208 + oc + 64 * oi] = fmaxf(acc[oi][r] + bb, 0.f);
    }
    __syncthreads();

    #pragma unroll
    for (int oi = 0; oi < 4; ++oi)
      #pragma unroll
      for (int r = 0; r < 4; ++r) acc[oi][r] = 0.f;
    for (int k4 = 0; k4 < 50; ++k4) {
      float xv[4][4];
      #pragma unroll
      for (int r = 0; r < 4; ++r) {
        f4v v = *(const f4v*)&h2[(4 * rg + r) * 208 + 4 * k4];
        xv[r][0] = v[0]; xv[r][1] = v[1]; xv[r][2] = v[2]; xv[r][3] = v[3];
      }
      #pragma unroll
      for (int kk = 0; kk < 4; ++kk) {
        const float* wr = W3 + (4 * k4 + kk) * 256 + oc;
        float w0 = wr[0], w1c = wr[64], w2c = wr[128], w3c = wr[192];
        #pragma unroll
        for (int r = 0; r < 4; ++r) {
          acc[0][r] = fmaf(xv[r][kk], w0, acc[0][r]);
          acc[1][r] = fmaf(xv[r][kk], w1c, acc[1][r]);
          acc[2][r] = fmaf(xv[r][kk], w2c, acc[2][r]);
          acc[3][r] = fmaf(xv[r][kk], w3c, acc[3][r]);
        }
      }
    }
    __syncthreads();   // reads of h2/xs done before ys overlays ubuf
    #pragma unroll
    for (int oi = 0; oi < 4; ++oi) {
      float bb = b3[oc + 64 * oi];
      #pragma unroll
      for (int r = 0; r < 4; ++r)
        ys[(4 * rg + r) * 260 + oc + 64 * oi] = acc[oi][r] + bb;
    }
  }

  // ---- stage pre-split KAT fragments (wave wv handles U = 4wv..4wv+3) ----
  #pragma unroll
  for (int u = 0; u < 4; ++u) {
    const int U = 4 * wv + u;
    float v[8];
    #pragma unroll
    for (int j = 0; j < 8; ++j)
      v[j] = KAT[(size_t)(16 * U + l15) * 32 + 8 * quad + j];
    S8U h, l;
    #pragma unroll
    for (int d = 0; d < 4; ++d) split_pair(v[2 * d], v[2 * d + 1], h.u[d], l.u[d]);
    *(u4v*)&kfh[U * 256 + lane * 4] = h.v4;
    *(u4v*)&kfl[U * 256 + lane * 4] = l.v4;
  }
  __syncthreads();   // MLP ys + KAT frags visible to wave 0

  if (wv != 0) return;   // waves 1-3 done; wave 0 iterates alone, barrier-free

  // ---- wave-0 invariant A-op fragments + binit (registers) ----
  short8 aah[2][8], aal[2][8];
  f4v binit[2];
  #pragma unroll
  for (int T = 0; T < 2; ++T) {
    #pragma unroll
    for (int s = 0; s < 8; ++s) {
      const float* ap = A + (size_t)(l15 + 16 * T) * 256 + 32 * s + 8 * quad;
      float v[8];
      #pragma unroll
      for (int j = 0; j < 8; ++j) v[j] = ap[j];
      split8(v, aah[T][s], aal[T][s]);
    }
    f4v bv = *(const f4v*)&bmat[(size_t)(row0 + l15) * 32 + 16 * T + 4 * quad];
    binit[T] = -bv;
  }

  // lane-dependent part of the zfrag offset (U part is a compile-time imm)
  const int zlane = (quad >> 1) * 64 + l15 * 4 + 2 * (quad & 1);

  // ---- init z from ys; publish zfrag (single-buffered: same-wave order) ----
  f4v zr[16];
  #pragma unroll
  for (int U = 0; U < 16; ++U)
    zr[U] = *(const f4v*)&ys[l15 * 260 + 16 * U + 4 * quad];
  #pragma unroll
  for (int U = 0; U < 16; ++U) {
    const int zo = (((U >> 3) * 4 + ((U >> 1) & 3)) * 2) * 256 + (U & 1) * 128 + zlane;
    unsigned h0, l0, h1_, l1_;
    split_pair(zr[U][0], zr[U][1], h0, l0);
    split_pair(zr[U][2], zr[U][3], h1_, l1_);
    u2v hv; hv[0] = h0; hv[1] = h1_;
    u2v lv; lv[0] = l0; lv[1] = l1_;
    *(u2v*)&zfrag[zo] = hv;
    *(u2v*)&zfrag[zo + 256] = lv;
  }

  const int niter = n_iter_p[0];

  for (int it = 0; it <= niter; ++it) {
    // ---- read z fragments (written by this wave last iteration) ----
    short8 zfh[8], zfl[8];
    #pragma unroll
    for (int s = 0; s < 8; ++s) {
      zfh[s] = *(const short8*)&zfrag[(s * 2 + 0) * 256 + lane * 4];
      zfl[s] = *(const short8*)&zfrag[(s * 2 + 1) * 256 + lane * 4];
    }

    // ---- phase A: full-K r = A z^T - b (both m-tiles, 48 MFMA) ----
    f4v c0[2], c1[2];
    c0[0] = binit[0]; c0[1] = binit[1];
    c1[0] = f4v{0.f, 0.f, 0.f, 0.f};
    c1[1] = f4v{0.f, 0.f, 0.f, 0.f};
    #pragma unroll
    for (int s = 0; s < 8; ++s) {
      #pragma unroll
      for (int T = 0; T < 2; ++T) {
        f4v cc = (s & 1) ? c1[T] : c0[T];
        cc = mfma16(aah[T][s], zfh[s], cc);
        cc = mfma16(aal[T][s], zfh[s], cc);
        cc = mfma16(aah[T][s], zfl[s], cc);
        if (s & 1) c1[T] = cc; else c0[T] = cc;
      }
    }

    // ---- same-wave r roundtrip: C-layout store -> B-op layout load ----
    #pragma unroll
    for (int T = 0; T < 2; ++T) {
      f4v rA = c0[T] + c1[T];
      *(f4v*)&rb[l15 * 36 + 16 * T + 4 * quad] = rA;   // r[i][m]
    }
    f4v ra  = *(const f4v*)&rb[l15 * 36 + 8 * quad];
    f4v rbv = *(const f4v*)&rb[l15 * 36 + 8 * quad + 4];
    float rv[8] = {ra[0], ra[1], ra[2], ra[3], rbv[0], rbv[1], rbv[2], rbv[3]};
    short8 rh, rl;
    split8(rv, rh, rl);

    // ---- phase B + update per U-tile (48 MFMA; no barrier) ----
    if (it < niter) {
      #pragma unroll
      for (int U = 0; U < 16; ++U) {
        short8 kh = *(const short8*)&kfh[U * 256 + lane * 4];
        short8 kl = *(const short8*)&kfl[U * 256 + lane * 4];
        f4v cc = {0.f, 0.f, 0.f, 0.f};
        cc = mfma16(kh, rh, cc);
        cc = mfma16(kl, rh, cc);
        cc = mfma16(kh, rl, cc);
        f4v z = zr[U];
        #pragma unroll
        for (int r = 0; r < 4; ++r) {
          float vv = fminf(fmaxf(z[r] - 2.f * cc[r], 0.f), 1.f);  // clip(2u-z)
          z[r] = fmaf(1.7f, vv - z[r] + cc[r], z[r]);             // z+=1.7(v-u)
        }
        zr[U] = z;
        const int zo = (((U >> 3) * 4 + ((U >> 1) & 3)) * 2) * 256 + (U & 1) * 128 + zlane;
        unsigned h0, l0, h1_, l1_;
        split_pair(z[0], z[1], h0, l0);
        split_pair(z[2], z[3], h1_, l1_);
        u2v hv; hv[0] = h0; hv[1] = h1_;
        u2v lv; lv[0] = l0; lv[1] = l1_;
        *(u2v*)&zfrag[zo] = hv;
        *(u2v*)&zfrag[zo + 256] = lv;
      }
    } else {
      #pragma unroll
      for (int U = 0; U < 16; ++U) {
        short8 kh = *(const short8*)&kfh[U * 256 + lane * 4];
        short8 kl = *(const short8*)&kfl[U * 256 + lane * 4];
        f4v cc = {0.f, 0.f, 0.f, 0.f};
        cc = mfma16(kh, rh, cc);
        cc = mfma16(kl, rh, cc);
        cc = mfma16(kh, rl, cc);
        f4v ov;
        #pragma unroll
        for (int r = 0; r < 4; ++r) ov[r] = zr[U][r] - cc[r];
        *(f4v*)&out[(size_t)(row0 + l15) * 256 + 16 * U + 4 * quad] = ov;
      }
    }
  }
}

// ---------------------------------------------------------------------------
extern "C" void kernel_launch(void* const* d_in, const int* in_sizes, int n_in,
                              void* d_out, int out_size, void* d_ws, size_t ws_size,
                              hipStream_t stream) {
  const float* x    = (const float*)d_in[0];
  const float* bmat = (const float*)d_in[1];
  const float* W1   = (const float*)d_in[2];
  const float* b1   = (const float*)d_in[3];
  const float* W2   = (const float*)d_in[4];
  const float* b2   = (const float*)d_in[5];
  const float* W3   = (const float*)d_in[6];
  const float* b3   = (const float*)d_in[7];
  const float* A    = (const float*)d_in[8];
  const int*  n_it  = (const int*)d_in[10];
  float* KAT = (float*)d_ws;          // 256*32 floats = 32 KB
  float* out = (float*)d_out;

  hipLaunchKernelGGL(k_prep, dim3(1), dim3(256), 0, stream, A, KAT);
  hipLaunchKernelGGL(k_main, dim3(Bn / TR), dim3(256), 0, stream,
                     x, bmat, W1, b1, W2, b2, W3, b3, A, KAT, n_it, out);
}

// Round 12
// 247.734 us; speedup vs baseline: 1.5663x; 1.5663x over previous
//
#include <hip/hip_runtime.h>
#include <hip/hip_bf16.h>

typedef float    f4v    __attribute__((ext_vector_type(4)));
typedef short    short8 __attribute__((ext_vector_type(8)));
typedef unsigned u2v    __attribute__((ext_vector_type(2)));

constexpr int Bn = 4096, TR = 16;

// ---- split-bf16 helpers ----------------------------------------------------
__device__ inline unsigned cvt2(float x, float y) {
  union { __hip_bfloat162 h; unsigned u; } c;
  c.h = __float22bfloat162_rn(float2{x, y});
  return c.u;   // low16 = bf16(x), high16 = bf16(y)
}
__device__ inline void split_pair(float x, float y, unsigned& hp, unsigned& lp) {
  hp = cvt2(x, y);
  float hx = __uint_as_float(hp << 16);
  float hy = __uint_as_float(hp & 0xffff0000u);
  lp = cvt2(x - hx, y - hy);
}
union S8U { unsigned u[4]; short8 s; };
__device__ inline void split8(const float v[8], short8& hi, short8& lo) {
  S8U h, l;
  #pragma unroll
  for (int d = 0; d < 4; ++d) split_pair(v[2 * d], v[2 * d + 1], h.u[d], l.u[d]);
  hi = h.s; lo = l.s;
}
__device__ inline void split8p(const float* p, short8& hi, short8& lo) {
  f4v a = *(const f4v*)p, b = *(const f4v*)(p + 4);
  float v[8] = {a[0], a[1], a[2], a[3], b[0], b[1], b[2], b[3]};
  split8(v, hi, lo);
}
__device__ inline f4v mfma16(short8 a, short8 b, f4v c) {
  return __builtin_amdgcn_mfma_f32_16x16x32_bf16(a, b, c, 0, 0, 0);
}
__device__ __attribute__((always_inline)) inline f4v gdot8(
    const short8 (&ah)[8], const short8 (&al)[8],
    const short8 (&bh)[8], const short8 (&bl)[8]) {
  f4v c = {0.f, 0.f, 0.f, 0.f};
  #pragma unroll
  for (int s = 0; s < 8; ++s) {
    c = mfma16(ah[s], bh[s], c);
    c = mfma16(al[s], bh[s], c);
    c = mfma16(ah[s], bl[s], c);
  }
  return c;
}

// ---------------------------------------------------------------------------
// k_prep: KAT[n][m] = (inv(A A^T + 1e-6 I) @ A)^T -> d_ws. 1 block, 256 thr.
// (verified: G via MFMA, Gauss-Jordan on wave 0 via unrolled shuffles.)
// ---------------------------------------------------------------------------
__global__ __launch_bounds__(256) void k_prep(const float* __restrict__ A,
                                              float* __restrict__ KAT) {
  __shared__ __align__(16) float As[32 * 256];
  __shared__ float Gm[32 * 68];
  __shared__ float GinvL[32 * 32];

  const int t = threadIdx.x;
  const int lane = t & 63, wv = t >> 6, quad = lane >> 4, l15 = lane & 15;
  const int T = wv & 1, kh = wv >> 1;

  for (int i = t; i < 2048; i += 256)
    ((f4v*)As)[i] = ((const f4v*)A)[i];
  __syncthreads();

  {
    short8 afh[2][8], afl[2][8];
    #pragma unroll
    for (int tt = 0; tt < 2; ++tt)
      #pragma unroll
      for (int s = 0; s < 8; ++s)
        split8p(As + (l15 + 16 * tt) * 256 + 32 * s + 8 * quad,
                afh[tt][s], afl[tt][s]);
    f4v cg;
    if      (wv == 0) cg = gdot8(afh[0], afl[0], afh[0], afl[0]);
    else if (wv == 1) cg = gdot8(afh[1], afl[1], afh[0], afl[0]);
    else if (wv == 2) cg = gdot8(afh[0], afl[0], afh[1], afl[1]);
    else              cg = gdot8(afh[1], afl[1], afh[1], afl[1]);
    #pragma unroll
    for (int r = 0; r < 4; ++r) {
      int gi = 16 * T + 4 * quad + r, gj = 16 * kh + l15;
      Gm[gi * 68 + gj]      = cg[r] + (gi == gj ? 1e-6f : 0.f);
      Gm[gi * 68 + 32 + gj] = (gi == gj) ? 1.f : 0.f;
    }
  }
  __syncthreads();

  if (wv == 0) {
    float gcol[32];
    #pragma unroll
    for (int i = 0; i < 32; ++i) gcol[i] = Gm[i * 68 + lane];
    #pragma unroll
    for (int k = 0; k < 32; ++k) {
      float ckk  = __shfl(gcol[k], k);
      float ipiv = 1.f / ckk;
      float pivj = gcol[k] * ipiv;
      gcol[k] = pivj;
      #pragma unroll
      for (int i = 0; i < 32; ++i) {
        if (i == k) continue;
        float cki = __shfl(gcol[i], k);
        gcol[i] = fmaf(-cki, pivj, gcol[i]);
      }
    }
    if (lane >= 32) {
      #pragma unroll
      for (int i = 0; i < 32; ++i) GinvL[i * 32 + (lane - 32)] = gcol[i];
    }
  }
  __syncthreads();

  {
    float res[32];
    #pragma unroll
    for (int m = 0; m < 32; ++m) res[m] = 0.f;
    for (int p = 0; p < 32; ++p) {
      float av = As[p * 256 + t];
      #pragma unroll
      for (int m4 = 0; m4 < 8; ++m4) {
        f4v g = *(const f4v*)&GinvL[p * 32 + 4 * m4];
        res[4 * m4 + 0] = fmaf(av, g[0], res[4 * m4 + 0]);
        res[4 * m4 + 1] = fmaf(av, g[1], res[4 * m4 + 1]);
        res[4 * m4 + 2] = fmaf(av, g[2], res[4 * m4 + 2]);
        res[4 * m4 + 3] = fmaf(av, g[3], res[4 * m4 + 3]);
      }
    }
    #pragma unroll
    for (int m4 = 0; m4 < 8; ++m4) {
      f4v v = {res[4 * m4], res[4 * m4 + 1], res[4 * m4 + 2], res[4 * m4 + 3]};
      *(f4v*)&KAT[t * 32 + 4 * m4] = v;
    }
  }
}

// ---------------------------------------------------------------------------
// k_main: 1024 threads (16 waves = 4 waves/SIMD), TR=16, grid 256.
// Phase A (waves 0-3, one per SIMD): (T=wv&1, kh=wv>>1) partial
//   r^T = A z^T - b^T, 12 MFMA -> rfrag (R5-verified mapping).
// Phase B (all 16 waves, 1 U-tile each): w^T = KA^T r^T (6 MFMA), z update
//   in registers, publish to single-buffered zfrag (safe: 2 barriers order
//   A-reads < B-writes and B-reads < next A-writes).
// ---------------------------------------------------------------------------
__global__ __launch_bounds__(1024, 4) void k_main(
    const float* __restrict__ x,  const float* __restrict__ bmat,
    const float* __restrict__ W1, const float* __restrict__ b1,
    const float* __restrict__ W2, const float* __restrict__ b2,
    const float* __restrict__ W3, const float* __restrict__ b3,
    const float* __restrict__ A,  const float* __restrict__ KAT,
    const int* __restrict__ n_iter_p, float* __restrict__ out) {

  // ubuf[0..8768): MLP scratch (xs/h1/h2), then ys[16][260] in [0..4160).
  // zfrag overlays ubuf[4416..8512) (h1/h2 region, dead after MLP).
  __shared__ __align__(16) float    ubuf[8768];
  __shared__ __align__(16) unsigned rfrag[1024];   // [kh][hi/lo][256 dwords]

  const int t = threadIdx.x;
  const int lane = t & 63, wv = t >> 6, quad = lane >> 4, l15 = lane & 15;
  const int row0 = blockIdx.x * TR;

  float* xs = ubuf;            // [16][132]
  float* h1 = ubuf + 2112;     // [16][208]
  float* h2 = ubuf + 5440;     // [16][208]
  float* ys = ubuf;            // [16][260]
  unsigned* zfrag = (unsigned*)(ubuf + 4416);   // 4096 dwords

  if (t < 512) {
    int r = t >> 5, c4 = t & 31;
    *(f4v*)&xs[r * 132 + 4 * c4] = *(const f4v*)&x[(size_t)(row0 + r) * 128 + 4 * c4];
  }
  __syncthreads();

  // ---- MLP: 1 row per wave (16 waves) ----
  {
    const int rg = wv, oc = lane;
    const bool g3 = (oc < 8);    // HID=200: col oc+192 valid iff oc<8
    float acc[4];

    // L1: 128 -> 200, relu
    #pragma unroll
    for (int oi = 0; oi < 4; ++oi) acc[oi] = 0.f;
    for (int k4 = 0; k4 < 32; ++k4) {
      f4v xv = *(const f4v*)&xs[rg * 132 + 4 * k4];
      #pragma unroll
      for (int kk = 0; kk < 4; ++kk) {
        const float* wr = W1 + (4 * k4 + kk) * 200 + oc;
        acc[0] = fmaf(xv[kk], wr[0], acc[0]);
        acc[1] = fmaf(xv[kk], wr[64], acc[1]);
        acc[2] = fmaf(xv[kk], wr[128], acc[2]);
        acc[3] = fmaf(xv[kk], g3 ? wr[192] : 0.f, acc[3]);
      }
    }
    #pragma unroll
    for (int oi = 0; oi < 4; ++oi) {
      if (oi == 3 && !g3) continue;
      h1[rg * 208 + oc + 64 * oi] = fmaxf(acc[oi] + b1[oc + 64 * oi], 0.f);
    }
    __syncthreads();

    // L2: 200 -> 200, relu
    #pragma unroll
    for (int oi = 0; oi < 4; ++oi) acc[oi] = 0.f;
    for (int k4 = 0; k4 < 50; ++k4) {
      f4v xv = *(const f4v*)&h1[rg * 208 + 4 * k4];
      #pragma unroll
      for (int kk = 0; kk < 4; ++kk) {
        const float* wr = W2 + (4 * k4 + kk) * 200 + oc;
        acc[0] = fmaf(xv[kk], wr[0], acc[0]);
        acc[1] = fmaf(xv[kk], wr[64], acc[1]);
        acc[2] = fmaf(xv[kk], wr[128], acc[2]);
        acc[3] = fmaf(xv[kk], g3 ? wr[192] : 0.f, acc[3]);
      }
    }
    __syncthreads();   // h1 reads done before h2 writes overlap? (h1,h2 disjoint) -- keep for safety
    #pragma unroll
    for (int oi = 0; oi < 4; ++oi) {
      if (oi == 3 && !g3) continue;
      h2[rg * 208 + oc + 64 * oi] = fmaxf(acc[oi] + b2[oc + 64 * oi], 0.f);
    }
    __syncthreads();

    // L3: 200 -> 256 (no relu) -> ys
    #pragma unroll
    for (int oi = 0; oi < 4; ++oi) acc[oi] = 0.f;
    for (int k4 = 0; k4 < 50; ++k4) {
      f4v xv = *(const f4v*)&h2[rg * 208 + 4 * k4];
      #pragma unroll
      for (int kk = 0; kk < 4; ++kk) {
        const float* wr = W3 + (4 * k4 + kk) * 256 + oc;
        acc[0] = fmaf(xv[kk], wr[0], acc[0]);
        acc[1] = fmaf(xv[kk], wr[64], acc[1]);
        acc[2] = fmaf(xv[kk], wr[128], acc[2]);
        acc[3] = fmaf(xv[kk], wr[192], acc[3]);
      }
    }
    __syncthreads();   // all xs/h1/h2 reads done before ys overlays ubuf
    #pragma unroll
    for (int oi = 0; oi < 4; ++oi)
      ys[rg * 260 + oc + 64 * oi] = acc[oi] + b3[oc + 64 * oi];
  }
  __syncthreads();

  // ---- iteration-invariant operand fragments ----
  const int T  = wv & 1;         // phase-A m-tile (waves 0-3)
  const int kh = wv >> 1;        // phase-A K-half

  short8 aah[4], aal[4];
  f4v binit = {0.f, 0.f, 0.f, 0.f};
  if (wv < 4) {
    #pragma unroll
    for (int s = 0; s < 4; ++s) {
      const float* ap = A + (size_t)(l15 + 16 * T) * 256 + 128 * kh + 32 * s + 8 * quad;
      float v[8];
      #pragma unroll
      for (int j = 0; j < 8; ++j) v[j] = ap[j];
      split8(v, aah[s], aal[s]);
    }
    if (wv < 2) {   // kh==0 carries -b
      f4v bv = *(const f4v*)&bmat[(size_t)(row0 + l15) * 32 + 16 * T + 4 * quad];
      binit = -bv;
    }
  }

  short8 kanh, kanl;             // phase-B A-op: KAT n-tile U = wv
  {
    const float* kp = KAT + (size_t)(16 * wv + l15) * 32 + 8 * quad;
    float v[8];
    #pragma unroll
    for (int j = 0; j < 8; ++j) v[j] = kp[j];
    split8(v, kanh, kanl);
  }

  // ---- zfrag write offset for U = wv (R5-verified formula) ----
  const int U = wv;
  const int qp = 2 * (U & 1) + (quad >> 1);
  const int zoff = (((U >> 3) * 4 + ((U >> 1) & 3)) * 2) * 256
                   + qp * 64 + l15 * 4 + 2 * (quad & 1);

  // ---- init z regs from ys; publish zfrag ----
  float zr[4];
  {
    f4v yv = *(const f4v*)&ys[l15 * 260 + 16 * U + 4 * quad];
    #pragma unroll
    for (int r = 0; r < 4; ++r) zr[r] = yv[r];
  }
  __syncthreads();   // ys reads done before zfrag (overlapping region is h1/h2, but keep ordering clean)
  {
    unsigned h0, l0, h1_, l1_;
    split_pair(zr[0], zr[1], h0, l0);
    split_pair(zr[2], zr[3], h1_, l1_);
    u2v hv; hv[0] = h0; hv[1] = h1_;
    u2v lv; lv[0] = l0; lv[1] = l1_;
    *(u2v*)&zfrag[zoff] = hv;
    *(u2v*)&zfrag[zoff + 256] = lv;
  }
  __syncthreads();

  const int niter = n_iter_p[0];

  for (int it = 0; it <= niter; ++it) {
    // ======== Phase A (waves 0-3): partial r^T = A z^T - b^T ========
    if (wv < 4) {
      short8 zfh[4], zfl[4];
      #pragma unroll
      for (int s = 0; s < 4; ++s) {
        zfh[s] = *(const short8*)&zfrag[((kh * 4 + s) * 2 + 0) * 256 + lane * 4];
        zfl[s] = *(const short8*)&zfrag[((kh * 4 + s) * 2 + 1) * 256 + lane * 4];
      }
      f4v c0 = binit, c1 = {0.f, 0.f, 0.f, 0.f};
      #pragma unroll
      for (int s = 0; s < 4; ++s) {
        f4v cc = (s & 1) ? c1 : c0;
        cc = mfma16(aah[s], zfh[s], cc);
        cc = mfma16(aal[s], zfh[s], cc);
        cc = mfma16(aah[s], zfl[s], cc);
        if (s & 1) c1 = cc; else c0 = cc;
      }
      f4v rA = c0 + c1;
      unsigned h0, l0, h1_, l1_;
      split_pair(rA[0], rA[1], h0, l0);
      split_pair(rA[2], rA[3], h1_, l1_);
      const int lanep = (2 * T + (quad >> 1)) * 16 + l15;
      const int rb = kh * 512 + lanep * 4 + 2 * (quad & 1);
      u2v hv; hv[0] = h0; hv[1] = h1_;
      u2v lv; lv[0] = l0; lv[1] = l1_;
      *(u2v*)&rfrag[rb] = hv;
      *(u2v*)&rfrag[rb + 256] = lv;
    }
    __syncthreads();   // barrier #1: rfrag ready; zfrag reads complete

    // ======== Phase B (all 16 waves): w^T = KA^T r^T for U = wv ========
    const short8 rh0 = *(const short8*)&rfrag[0 * 256 + lane * 4];
    const short8 rl0 = *(const short8*)&rfrag[1 * 256 + lane * 4];
    const short8 rh1 = *(const short8*)&rfrag[2 * 256 + lane * 4];
    const short8 rl1 = *(const short8*)&rfrag[3 * 256 + lane * 4];
    f4v cc = {0.f, 0.f, 0.f, 0.f};
    cc = mfma16(kanh, rh0, cc);
    cc = mfma16(kanl, rh0, cc);
    cc = mfma16(kanh, rl0, cc);
    cc = mfma16(kanh, rh1, cc);
    cc = mfma16(kanl, rh1, cc);
    cc = mfma16(kanh, rl1, cc);

    if (it < niter) {
      #pragma unroll
      for (int r = 0; r < 4; ++r) {
        float z = zr[r], wvv = cc[r];
        float vv = fminf(fmaxf(z - 2.f * wvv, 0.f), 1.f);  // clip(2u - z)
        zr[r] = fmaf(1.7f, vv - z + wvv, z);               // z += 1.7*(v-u)
      }
      unsigned h0, l0, h1_, l1_;
      split_pair(zr[0], zr[1], h0, l0);
      split_pair(zr[2], zr[3], h1_, l1_);
      u2v hv; hv[0] = h0; hv[1] = h1_;
      u2v lv; lv[0] = l0; lv[1] = l1_;
      *(u2v*)&zfrag[zoff] = hv;
      *(u2v*)&zfrag[zoff + 256] = lv;
      __syncthreads();   // barrier #2: z published; rfrag reads complete
    } else {
      f4v ov;
      #pragma unroll
      for (int r = 0; r < 4; ++r) ov[r] = zr[r] - cc[r];
      *(f4v*)&out[(size_t)(row0 + l15) * 256 + 16 * U + 4 * quad] = ov;
    }
  }
}

// ---------------------------------------------------------------------------
extern "C" void kernel_launch(void* const* d_in, const int* in_sizes, int n_in,
                              void* d_out, int out_size, void* d_ws, size_t ws_size,
                              hipStream_t stream) {
  const float* x    = (const float*)d_in[0];
  const float* bmat = (const float*)d_in[1];
  const float* W1   = (const float*)d_in[2];
  const float* b1   = (const float*)d_in[3];
  const float* W2   = (const float*)d_in[4];
  const float* b2   = (const float*)d_in[5];
  const float* W3   = (const float*)d_in[6];
  const float* b3   = (const float*)d_in[7];
  const float* A    = (const float*)d_in[8];
  const int*  n_it  = (const int*)d_in[10];
  float* KAT = (float*)d_ws;          // 256*32 floats = 32 KB
  float* out = (float*)d_out;

  hipLaunchKernelGGL(k_prep, dim3(1), dim3(256), 0, stream, A, KAT);
  hipLaunchKernelGGL(k_main, dim3(Bn / TR), dim3(1024), 0, stream,
                     x, bmat, W1, b1, W2, b2, W3, b3, A, KAT, n_it, out);
}

// Round 13
// 243.593 us; speedup vs baseline: 1.5929x; 1.0170x over previous
//
#include <hip/hip_runtime.h>
#include <hip/hip_bf16.h>

typedef float    f4v    __attribute__((ext_vector_type(4)));
typedef short    short8 __attribute__((ext_vector_type(8)));
typedef unsigned u2v    __attribute__((ext_vector_type(2)));

constexpr int Bn = 4096, TR = 16;

// ---- split-bf16 helpers ----------------------------------------------------
__device__ inline unsigned cvt2(float x, float y) {
  union { __hip_bfloat162 h; unsigned u; } c;
  c.h = __float22bfloat162_rn(float2{x, y});
  return c.u;   // low16 = bf16(x), high16 = bf16(y)
}
__device__ inline void split_pair(float x, float y, unsigned& hp, unsigned& lp) {
  hp = cvt2(x, y);
  float hx = __uint_as_float(hp << 16);
  float hy = __uint_as_float(hp & 0xffff0000u);
  lp = cvt2(x - hx, y - hy);
}
union S8U { unsigned u[4]; short8 s; };
__device__ inline void split8(const float v[8], short8& hi, short8& lo) {
  S8U h, l;
  #pragma unroll
  for (int d = 0; d < 4; ++d) split_pair(v[2 * d], v[2 * d + 1], h.u[d], l.u[d]);
  hi = h.s; lo = l.s;
}
__device__ inline void split8p(const float* p, short8& hi, short8& lo) {
  f4v a = *(const f4v*)p, b = *(const f4v*)(p + 4);
  float v[8] = {a[0], a[1], a[2], a[3], b[0], b[1], b[2], b[3]};
  split8(v, hi, lo);
}
__device__ inline f4v mfma16(short8 a, short8 b, f4v c) {
  return __builtin_amdgcn_mfma_f32_16x16x32_bf16(a, b, c, 0, 0, 0);
}

// ---------------------------------------------------------------------------
// k_fused: grid 256 x 512 threads (8 waves). Per-block prep (VALU G + shuffle
// Gauss-Jordan + direct per-thread kan fragments; no KAT materialization, no
// register blob), then MLP, then R8's verified 2-barrier iteration loop.
// ---------------------------------------------------------------------------
__global__ __launch_bounds__(512, 1) void k_fused(
    const float* __restrict__ x,  const float* __restrict__ bmat,
    const float* __restrict__ W1, const float* __restrict__ b1,
    const float* __restrict__ W2, const float* __restrict__ b2,
    const float* __restrict__ W3, const float* __restrict__ b3,
    const float* __restrict__ A,  const int* __restrict__ n_iter_p,
    float* __restrict__ out) {

  __shared__ __align__(16) float    ubuf[8768];    // A[32][256] -> MLP -> ys
  __shared__ __align__(16) unsigned zfrag[4096];   // prep: Gm[32*68]+GinvL[1024]
  __shared__ __align__(16) unsigned rfrag[512];    // loop: r frags

  const int t = threadIdx.x;
  const int lane = t & 63, wv = t >> 6, quad = lane >> 4, l15 = lane & 15;
  const int row0 = blockIdx.x * TR;

  float* Ald   = ubuf;                       // A 32x256 (prep phase)
  float* Gm    = (float*)zfrag;              // [32][68] augmented [G|I]
  float* GinvL = (float*)zfrag + 2240;       // [32][32]

  // ---- 1. stage A into LDS ----
  for (int i = t; i < 2048; i += 512)
    ((f4v*)Ald)[i] = ((const f4v*)A)[i];
  __syncthreads();

  // ---- 2. G = A A^T + eps I (VALU, 2 entries/thread); extract A-frags ----
  #pragma unroll
  for (int e = 0; e < 2; ++e) {
    const int idx = t + 512 * e, gi = idx >> 5, gj = idx & 31;
    f4v acc = {0.f, 0.f, 0.f, 0.f};
    const f4v* ai = (const f4v*)(Ald + gi * 256);
    const f4v* aj = (const f4v*)(Ald + gj * 256);
    for (int k = 0; k < 64; ++k) acc += ai[k] * aj[k];
    float s = acc[0] + acc[1] + acc[2] + acc[3];
    if (gi == gj) s += 1e-6f;
    Gm[gi * 68 + gj] = s;
    Gm[gi * 68 + 32 + gj] = (gi == gj) ? 1.f : 0.f;
  }

  // phase-A fragments (waves 0,1 = m-tile T; full K) from LDS A
  const int T = wv;   // valid for wv<2
  short8 aah[8], aal[8];
  f4v binit = {0.f, 0.f, 0.f, 0.f};
  if (wv < 2) {
    #pragma unroll
    for (int s = 0; s < 8; ++s)
      split8p(Ald + (l15 + 16 * T) * 256 + 32 * s + 8 * quad, aah[s], aal[s]);
    f4v bv = *(const f4v*)&bmat[(size_t)(row0 + l15) * 32 + 16 * T + 4 * quad];
    binit = -bv;
  }
  __syncthreads();

  // ---- 3. Gauss-Jordan on wave 0 (verified shuffle routine) ----
  if (wv == 0) {
    float gcol[32];
    #pragma unroll
    for (int i = 0; i < 32; ++i) gcol[i] = Gm[i * 68 + lane];
    #pragma unroll
    for (int k = 0; k < 32; ++k) {
      float ckk  = __shfl(gcol[k], k);
      float ipiv = 1.f / ckk;
      float pivj = gcol[k] * ipiv;
      gcol[k] = pivj;
      #pragma unroll
      for (int i = 0; i < 32; ++i) {
        if (i == k) continue;
        float cki = __shfl(gcol[i], k);
        gcol[i] = fmaf(-cki, pivj, gcol[i]);
      }
    }
    if (lane >= 32) {
      #pragma unroll
      for (int i = 0; i < 32; ++i) GinvL[i * 32 + (lane - 32)] = gcol[i];
    }
  }
  __syncthreads();

  // ---- 4. kan fragments directly: KAT[n][8q+j] = sum_p A[p][n] Ginv[p][8q+j]
  short8 kanh[2], kanl[2];
  #pragma unroll
  for (int u = 0; u < 2; ++u) {
    const int n = 16 * (2 * wv + u) + l15;
    float acc[8];
    #pragma unroll
    for (int j = 0; j < 8; ++j) acc[j] = 0.f;
    for (int p = 0; p < 32; ++p) {
      float av = Ald[p * 256 + n];
      f4v g0 = *(const f4v*)&GinvL[p * 32 + 8 * quad];
      f4v g1 = *(const f4v*)&GinvL[p * 32 + 8 * quad + 4];
      acc[0] = fmaf(av, g0[0], acc[0]); acc[1] = fmaf(av, g0[1], acc[1]);
      acc[2] = fmaf(av, g0[2], acc[2]); acc[3] = fmaf(av, g0[3], acc[3]);
      acc[4] = fmaf(av, g1[0], acc[4]); acc[5] = fmaf(av, g1[1], acc[5]);
      acc[6] = fmaf(av, g1[2], acc[6]); acc[7] = fmaf(av, g1[3], acc[7]);
    }
    split8(acc, kanh[u], kanl[u]);
  }
  __syncthreads();   // prep done; ubuf (A) + zfrag (Gm/GinvL) now reusable

  // ---- 5. MLP (R8-verified, 2 rows/wave) ----
  float* xs = ubuf;            // [16][132]
  float* h1 = ubuf + 2112;     // [16][208]
  float* h2 = ubuf + 5440;     // [16][208]
  float* ys = ubuf;            // [16][260]

  {
    int r = t >> 5, c4 = t & 31;
    *(f4v*)&xs[r * 132 + 4 * c4] = *(const f4v*)&x[(size_t)(row0 + r) * 128 + 4 * c4];
  }
  __syncthreads();

  {
    const int rg = wv, oc = lane;
    const bool g3 = (oc < 8);    // HID=200: col oc+192 valid iff oc<8
    float acc[4][2];

    // L1: 128 -> 200, relu
    #pragma unroll
    for (int oi = 0; oi < 4; ++oi) { acc[oi][0] = 0.f; acc[oi][1] = 0.f; }
    for (int k4 = 0; k4 < 32; ++k4) {
      f4v xv0 = *(const f4v*)&xs[(2 * rg + 0) * 132 + 4 * k4];
      f4v xv1 = *(const f4v*)&xs[(2 * rg + 1) * 132 + 4 * k4];
      #pragma unroll
      for (int kk = 0; kk < 4; ++kk) {
        const float* wr = W1 + (4 * k4 + kk) * 200 + oc;
        float w0 = wr[0], w1c = wr[64], w2c = wr[128];
        float w3c = g3 ? wr[192] : 0.f;
        acc[0][0] = fmaf(xv0[kk], w0, acc[0][0]);  acc[0][1] = fmaf(xv1[kk], w0, acc[0][1]);
        acc[1][0] = fmaf(xv0[kk], w1c, acc[1][0]); acc[1][1] = fmaf(xv1[kk], w1c, acc[1][1]);
        acc[2][0] = fmaf(xv0[kk], w2c, acc[2][0]); acc[2][1] = fmaf(xv1[kk], w2c, acc[2][1]);
        acc[3][0] = fmaf(xv0[kk], w3c, acc[3][0]); acc[3][1] = fmaf(xv1[kk], w3c, acc[3][1]);
      }
    }
    #pragma unroll
    for (int oi = 0; oi < 4; ++oi) {
      if (oi == 3 && !g3) continue;
      float bb = b1[oc + 64 * oi];
      h1[(2 * rg + 0) * 208 + oc + 64 * oi] = fmaxf(acc[oi][0] + bb, 0.f);
      h1[(2 * rg + 1) * 208 + oc + 64 * oi] = fmaxf(acc[oi][1] + bb, 0.f);
    }
    __syncthreads();

    // L2: 200 -> 200, relu
    #pragma unroll
    for (int oi = 0; oi < 4; ++oi) { acc[oi][0] = 0.f; acc[oi][1] = 0.f; }
    for (int k4 = 0; k4 < 50; ++k4) {
      f4v xv0 = *(const f4v*)&h1[(2 * rg + 0) * 208 + 4 * k4];
      f4v xv1 = *(const f4v*)&h1[(2 * rg + 1) * 208 + 4 * k4];
      #pragma unroll
      for (int kk = 0; kk < 4; ++kk) {
        const float* wr = W2 + (4 * k4 + kk) * 200 + oc;
        float w0 = wr[0], w1c = wr[64], w2c = wr[128];
        float w3c = g3 ? wr[192] : 0.f;
        acc[0][0] = fmaf(xv0[kk], w0, acc[0][0]);  acc[0][1] = fmaf(xv1[kk], w0, acc[0][1]);
        acc[1][0] = fmaf(xv0[kk], w1c, acc[1][0]); acc[1][1] = fmaf(xv1[kk], w1c, acc[1][1]);
        acc[2][0] = fmaf(xv0[kk], w2c, acc[2][0]); acc[2][1] = fmaf(xv1[kk], w2c, acc[2][1]);
        acc[3][0] = fmaf(xv0[kk], w3c, acc[3][0]); acc[3][1] = fmaf(xv1[kk], w3c, acc[3][1]);
      }
    }
    #pragma unroll
    for (int oi = 0; oi < 4; ++oi) {
      if (oi == 3 && !g3) continue;
      float bb = b2[oc + 64 * oi];
      h2[(2 * rg + 0) * 208 + oc + 64 * oi] = fmaxf(acc[oi][0] + bb, 0.f);
      h2[(2 * rg + 1) * 208 + oc + 64 * oi] = fmaxf(acc[oi][1] + bb, 0.f);
    }
    __syncthreads();

    // L3: 200 -> 256 (no relu) -> ys
    #pragma unroll
    for (int oi = 0; oi < 4; ++oi) { acc[oi][0] = 0.f; acc[oi][1] = 0.f; }
    for (int k4 = 0; k4 < 50; ++k4) {
      f4v xv0 = *(const f4v*)&h2[(2 * rg + 0) * 208 + 4 * k4];
      f4v xv1 = *(const f4v*)&h2[(2 * rg + 1) * 208 + 4 * k4];
      #pragma unroll
      for (int kk = 0; kk < 4; ++kk) {
        const float* wr = W3 + (4 * k4 + kk) * 256 + oc;
        float w0 = wr[0], w1c = wr[64], w2c = wr[128], w3c = wr[192];
        acc[0][0] = fmaf(xv0[kk], w0, acc[0][0]);  acc[0][1] = fmaf(xv1[kk], w0, acc[0][1]);
        acc[1][0] = fmaf(xv0[kk], w1c, acc[1][0]); acc[1][1] = fmaf(xv1[kk], w1c, acc[1][1]);
        acc[2][0] = fmaf(xv0[kk], w2c, acc[2][0]); acc[2][1] = fmaf(xv1[kk], w2c, acc[2][1]);
        acc[3][0] = fmaf(xv0[kk], w3c, acc[3][0]); acc[3][1] = fmaf(xv1[kk], w3c, acc[3][1]);
      }
    }
    __syncthreads();   // reads of h2/xs done before ys overlays ubuf
    #pragma unroll
    for (int oi = 0; oi < 4; ++oi) {
      float bb = b3[oc + 64 * oi];
      ys[(2 * rg + 0) * 260 + oc + 64 * oi] = acc[oi][0] + bb;
      ys[(2 * rg + 1) * 260 + oc + 64 * oi] = acc[oi][1] + bb;
    }
  }
  __syncthreads();

  // ---- zfrag write offsets (verified U-derived map) ----
  int zoff[2];
  #pragma unroll
  for (int u = 0; u < 2; ++u) {
    const int U = 2 * wv + u;
    const int qp = 2 * (U & 1) + (quad >> 1);
    zoff[u] = (((U >> 3) * 4 + ((U >> 1) & 3)) * 2) * 256
              + qp * 64 + l15 * 4 + 2 * (quad & 1);
  }

  // ---- init z regs from ys; publish zfrag ----
  float zr[2][4];
  #pragma unroll
  for (int u = 0; u < 2; ++u) {
    const int U = 2 * wv + u;
    f4v yv = *(const f4v*)&ys[l15 * 260 + 16 * U + 4 * quad];
    #pragma unroll
    for (int r = 0; r < 4; ++r) zr[u][r] = yv[r];
    unsigned h0, l0, h1_, l1_;
    split_pair(zr[u][0], zr[u][1], h0, l0);
    split_pair(zr[u][2], zr[u][3], h1_, l1_);
    u2v hv; hv[0] = h0; hv[1] = h1_;
    u2v lv; lv[0] = l0; lv[1] = l1_;
    *(u2v*)&zfrag[zoff[u]] = hv;
    *(u2v*)&zfrag[zoff[u] + 256] = lv;
  }
  __syncthreads();

  const int niter = n_iter_p[0];

  for (int it = 0; it <= niter; ++it) {
    // ======== Phase A (waves 0,1): full-K r^T = A z^T - b^T ========
    if (wv < 2) {
      short8 zfh[8], zfl[8];
      #pragma unroll
      for (int s = 0; s < 8; ++s) {
        zfh[s] = *(const short8*)&zfrag[(s * 2 + 0) * 256 + lane * 4];
        zfl[s] = *(const short8*)&zfrag[(s * 2 + 1) * 256 + lane * 4];
      }
      f4v c0 = binit;
      f4v c1 = {0.f, 0.f, 0.f, 0.f};
      f4v c2 = {0.f, 0.f, 0.f, 0.f};
      f4v c3 = {0.f, 0.f, 0.f, 0.f};
      #pragma unroll
      for (int s4 = 0; s4 < 2; ++s4) {   // 4 independent 6-deep chains
        int s = 4 * s4;
        c0 = mfma16(aah[s+0], zfh[s+0], c0);
        c1 = mfma16(aah[s+1], zfh[s+1], c1);
        c2 = mfma16(aah[s+2], zfh[s+2], c2);
        c3 = mfma16(aah[s+3], zfh[s+3], c3);
        c0 = mfma16(aal[s+0], zfh[s+0], c0);
        c1 = mfma16(aal[s+1], zfh[s+1], c1);
        c2 = mfma16(aal[s+2], zfh[s+2], c2);
        c3 = mfma16(aal[s+3], zfh[s+3], c3);
        c0 = mfma16(aah[s+0], zfl[s+0], c0);
        c1 = mfma16(aah[s+1], zfl[s+1], c1);
        c2 = mfma16(aah[s+2], zfl[s+2], c2);
        c3 = mfma16(aah[s+3], zfl[s+3], c3);
      }
      f4v rA = (c0 + c1) + (c2 + c3);
      unsigned h0, l0, h1_, l1_;
      split_pair(rA[0], rA[1], h0, l0);
      split_pair(rA[2], rA[3], h1_, l1_);
      const int rb = (2 * T + (quad >> 1)) * 64 + l15 * 4 + 2 * (quad & 1);
      u2v hv; hv[0] = h0; hv[1] = h1_;
      u2v lv; lv[0] = l0; lv[1] = l1_;
      *(u2v*)&rfrag[rb] = hv;
      *(u2v*)&rfrag[rb + 256] = lv;
    }
    __syncthreads();

    // ======== Phase B (all waves): w^T = KA^T r^T for U = 2wv, 2wv+1 ========
    const short8 rh = *(const short8*)&rfrag[0 * 256 + lane * 4];
    const short8 rl = *(const short8*)&rfrag[1 * 256 + lane * 4];
    f4v cB[2];
    #pragma unroll
    for (int u = 0; u < 2; ++u) {
      f4v cc = {0.f, 0.f, 0.f, 0.f};
      cc = mfma16(kanh[u], rh, cc);
      cc = mfma16(kanl[u], rh, cc);
      cc = mfma16(kanh[u], rl, cc);
      cB[u] = cc;
    }

    if (it < niter) {
      #pragma unroll
      for (int u = 0; u < 2; ++u) {
        #pragma unroll
        for (int r = 0; r < 4; ++r) {
          float z = zr[u][r], wvv = cB[u][r];
          float vv = fminf(fmaxf(z - 2.f * wvv, 0.f), 1.f);  // clip(2u - z)
          zr[u][r] = fmaf(1.7f, vv - z + wvv, z);            // z += 1.7*(v-u)
        }
        unsigned h0, l0, h1_, l1_;
        split_pair(zr[u][0], zr[u][1], h0, l0);
        split_pair(zr[u][2], zr[u][3], h1_, l1_);
        u2v hv; hv[0] = h0; hv[1] = h1_;
        u2v lv; lv[0] = l0; lv[1] = l1_;
        *(u2v*)&zfrag[zoff[u]] = hv;
        *(u2v*)&zfrag[zoff[u] + 256] = lv;
      }
      __syncthreads();
    } else {
      #pragma unroll
      for (int u = 0; u < 2; ++u) {
        const int U = 2 * wv + u;
        f4v ov;
        #pragma unroll
        for (int r = 0; r < 4; ++r) ov[r] = zr[u][r] - cB[u][r];
        *(f4v*)&out[(size_t)(row0 + l15) * 256 + 16 * U + 4 * quad] = ov;
      }
    }
  }
}

// ---------------------------------------------------------------------------
extern "C" void kernel_launch(void* const* d_in, const int* in_sizes, int n_in,
                              void* d_out, int out_size, void* d_ws, size_t ws_size,
                              hipStream_t stream) {
  const float* x    = (const float*)d_in[0];
  const float* bmat = (const float*)d_in[1];
  const float* W1   = (const float*)d_in[2];
  const float* b1   = (const float*)d_in[3];
  const float* W2   = (const float*)d_in[4];
  const float* b2   = (const float*)d_in[5];
  const float* W3   = (const float*)d_in[6];
  const float* b3   = (const float*)d_in[7];
  const float* A    = (const float*)d_in[8];
  const int*  n_it  = (const int*)d_in[10];
  float* out = (float*)d_out;

  hipLaunchKernelGGL(k_fused, dim3(Bn / TR), dim3(512), 0, stream,
                     x, bmat, W1, b1, W2, b2, W3, b3, A, n_it, out);
}